// Round 14
// baseline (230.197 us; speedup 1.0000x reference)
//
#include <hip/hip_runtime.h>
#include <hip/hip_bf16.h>
#include <hip/hip_fp16.h>

// GCN forward: emb-gather -> GCNConv(64->128) -> ReLU -> GCNConv(128->128) -> ReLU
//              -> global_max_pool -> Linear(128->10)
// N=100000, E=600000, VOCAB=5000, G=2000, C=10.
// Layer-1 agg in 64-dim embedding space (linearity) -> gemm1 -> h1 fp16.
// Layer-2: aggregate in h1-space (z = (di*(di*h1_i + sum dj*h1_j))@W2 + b2), fused
// gather (8-deep batched) + MFMA(W2) + relu + max-pool in ONE kernel. P never materialized.

typedef _Float16 h8 __attribute__((ext_vector_type(8)));
typedef float f32x4 __attribute__((ext_vector_type(4)));

// Zero deg, pool, Xagg pad rows.
__global__ __launch_bounds__(256) void k_zero(int4* __restrict__ deg4, int n4i,
                                              int4* __restrict__ pool4, int p4i,
                                              int4* __restrict__ xpad, int x4i) {
    int t = blockIdx.x * 256 + threadIdx.x;
    int4 z = make_int4(0, 0, 0, 0);
    if (t < n4i) deg4[t] = z;
    if (t < p4i) pool4[t] = z;
    if (t < x4i) xpad[t] = z;
}

// Fused: [0,gE) degree atomics; [gE,gE+nCast) e16 = fp16(emb); then W1T; then W2T.
__global__ __launch_bounds__(256) void k_degprep(const int* __restrict__ dst, int* __restrict__ deg, int E,
                                                 const float* __restrict__ emb, __half2* __restrict__ e16,
                                                 const float* __restrict__ W1, _Float16* __restrict__ W1T,
                                                 const float* __restrict__ W2, _Float16* __restrict__ W2T,
                                                 int nEmbF, int gE, int nCast) {
    int bid = blockIdx.x;
    if (bid < gE) {
        int e = bid * 256 + threadIdx.x;
        if (e < E) atomicAdd(&deg[dst[e]], 1);
    } else if (bid < gE + nCast) {
        int t = (bid - gE) * 256 + threadIdx.x;  // one thread = 4 floats
        if (t * 4 < nEmbF) {
            float4 v = *(const float4*)&emb[t * 4];
            e16[t * 2] = __floats2half2_rn(v.x, v.y);
            e16[t * 2 + 1] = __floats2half2_rn(v.z, v.w);
        }
    } else if (bid < gE + nCast + 32) {
        int t = (bid - gE - nCast) * 256 + threadIdx.x;  // 128*64
        int c = t >> 6, k = t & 63;
        W1T[c * 64 + k] = (_Float16)W1[k * 128 + c];
    } else {
        int t = (bid - gE - nCast - 32) * 256 + threadIdx.x;  // 128*128
        if (t < 128 * 128) {
            int c = t >> 7, k = t & 127;
            W2T[c * 128 + k] = (_Float16)W2[k * 128 + c];
        }
    }
}

// scan1 + dinv fused
__global__ __launch_bounds__(256) void k_scan1(const int* __restrict__ deg, int* __restrict__ exc,
                                               int* __restrict__ bsums, float* __restrict__ dinv, int N) {
    __shared__ int s[256];
    int i = blockIdx.x * 256 + threadIdx.x;
    int v = (i < N) ? deg[i] : 0;
    if (i < N) dinv[i] = rsqrtf((float)(v + 1));  // +1 self-loop
    s[threadIdx.x] = v;
    __syncthreads();
    for (int off = 1; off < 256; off <<= 1) {
        int t = (threadIdx.x >= (unsigned)off) ? s[threadIdx.x - off] : 0;
        __syncthreads();
        s[threadIdx.x] += t;
        __syncthreads();
    }
    if (i < N) exc[i] = s[threadIdx.x] - v;
    if (threadIdx.x == 255) bsums[blockIdx.x] = s[255];
}

__global__ __launch_bounds__(512) void k_scan2(int* __restrict__ bsums, int nb) {
    __shared__ int s[512];
    int i = threadIdx.x;
    int v = (i < nb) ? bsums[i] : 0;
    s[i] = v;
    __syncthreads();
    for (int off = 1; off < 512; off <<= 1) {
        int t = (i >= off) ? s[i - off] : 0;
        __syncthreads();
        s[i] += t;
        __syncthreads();
    }
    if (i < nb) bsums[i] = s[i] - v;
}

__global__ __launch_bounds__(256) void k_scan3(int* __restrict__ rowstart, int* __restrict__ cursor,
                                               const int* __restrict__ bsums, int N, int E) {
    int i = blockIdx.x * 256 + threadIdx.x;
    if (i < N) {
        int r = rowstart[i] + bsums[blockIdx.x];
        rowstart[i] = r;
        cursor[i] = r;
    }
    if (i == 0 && blockIdx.x == 0) rowstart[N] = E;
}

// CSR fill: rec[pos] = {x[src], dinv[src] bits, src, 0} — ONE 16B scattered store.
__global__ __launch_bounds__(256) void k_fill(const int* __restrict__ src, const int* __restrict__ dst,
                                              const int* __restrict__ x, const float* __restrict__ dinv,
                                              int* __restrict__ cursor, int4* __restrict__ rec, int E) {
    int e = blockIdx.x * 256 + threadIdx.x;
    if (e < E) {
        int d = dst[e];
        int s = src[e];
        int pos = atomicAdd(&cursor[d], 1);
        rec[pos] = make_int4(x[s], __float_as_int(dinv[s]), s, 0);
    }
}

// 64-dim embedding-space aggregation: Xagg[i] = di*(di*e16[x_i] + sum dj*e16[x_j]).
// 256 thr = 8 half-waves x 2 nodes; dual 8-deep clamped gather batches.
__global__ __launch_bounds__(256) void k_agge(const __half2* __restrict__ e16, const int* __restrict__ x,
                                              const float* __restrict__ dinv, const int* __restrict__ rs,
                                              const int4* __restrict__ rec, __half2* __restrict__ Xagg, int N) {
    int lane = threadIdx.x & 31;
    int n0 = (blockIdx.x * 8 + (threadIdx.x >> 5)) * 2;
    if (n0 >= N) return;
    int nB = (n0 + 1 < N) ? n0 + 1 : n0;
    int cA0 = rs[n0], cA1 = rs[n0 + 1];
    int cB0 = rs[nB], cB1 = rs[nB + 1];
    bool hasA = cA0 < cA1, hasB = cB0 < cB1;
    __half2 tA[8], tB[8];
    float wA[8], wB[8];
#pragma unroll
    for (int i = 0; i < 8; ++i) {
        int ei = cA0 + i;
        int ec = (ei < cA1) ? ei : (hasA ? cA1 - 1 : 0);
        int4 r2 = rec[ec];
        tA[i] = e16[(size_t)r2.x * 32 + lane];
        wA[i] = (ei < cA1) ? __int_as_float(r2.y) : 0.f;
    }
#pragma unroll
    for (int i = 0; i < 8; ++i) {
        int ei = cB0 + i;
        int ec = (ei < cB1) ? ei : (hasB ? cB1 - 1 : 0);
        int4 r2 = rec[ec];
        tB[i] = e16[(size_t)r2.x * 32 + lane];
        wB[i] = (ei < cB1) ? __int_as_float(r2.y) : 0.f;
    }
    float dA = dinv[n0], dB = dinv[nB];
    float2 sA = __half22float2(e16[(size_t)x[n0] * 32 + lane]);
    float2 sB = __half22float2(e16[(size_t)x[nB] * 32 + lane]);
    float aA0 = dA * sA.x, aA1 = dA * sA.y;
    float aB0 = dB * sB.x, aB1 = dB * sB.y;
#pragma unroll
    for (int i = 0; i < 8; ++i) {
        float2 tf = __half22float2(tA[i]);
        aA0 = fmaf(wA[i], tf.x, aA0);
        aA1 = fmaf(wA[i], tf.y, aA1);
    }
#pragma unroll
    for (int i = 0; i < 8; ++i) {
        float2 tf = __half22float2(tB[i]);
        aB0 = fmaf(wB[i], tf.x, aB0);
        aB1 = fmaf(wB[i], tf.y, aB1);
    }
    for (int e = cA0 + 8; e < cA1; e += 8) {
#pragma unroll
        for (int i = 0; i < 8; ++i) {
            int ei = e + i;
            int ec = (ei < cA1) ? ei : cA1 - 1;
            int4 r2 = rec[ec];
            tA[i] = e16[(size_t)r2.x * 32 + lane];
            wA[i] = (ei < cA1) ? __int_as_float(r2.y) : 0.f;
        }
#pragma unroll
        for (int i = 0; i < 8; ++i) {
            float2 tf = __half22float2(tA[i]);
            aA0 = fmaf(wA[i], tf.x, aA0);
            aA1 = fmaf(wA[i], tf.y, aA1);
        }
    }
    for (int e = cB0 + 8; e < cB1; e += 8) {
#pragma unroll
        for (int i = 0; i < 8; ++i) {
            int ei = e + i;
            int ec = (ei < cB1) ? ei : cB1 - 1;
            int4 r2 = rec[ec];
            tB[i] = e16[(size_t)r2.x * 32 + lane];
            wB[i] = (ei < cB1) ? __int_as_float(r2.y) : 0.f;
        }
#pragma unroll
        for (int i = 0; i < 8; ++i) {
            float2 tf = __half22float2(tB[i]);
            aB0 = fmaf(wB[i], tf.x, aB0);
            aB1 = fmaf(wB[i], tf.y, aB1);
        }
    }
    Xagg[(size_t)n0 * 32 + lane] = __floats2half2_rn(dA * aA0, dA * aA1);
    Xagg[(size_t)nB * 32 + lane] = __floats2half2_rn(dB * aB0, dB * aB1);
}

// h1 = relu(Xagg @ W1 + b1). 256 thr = 4 waves x 16 rows, block = 64 rows.
// Stores vectorized via LDS restage (4x16B per thread, coalesced).
__global__ __launch_bounds__(256) void k_gemm1(const _Float16* __restrict__ Xagg,
                                               const _Float16* __restrict__ W1T,
                                               const float* __restrict__ b1,
                                               _Float16* __restrict__ h1, int Npad) {
    __shared__ _Float16 Hs[64][136];
    int tid = threadIdx.x;
    int l = tid & 63, wid = tid >> 6;
    int r = l & 15, kg = l >> 4;
    int blk0 = blockIdx.x * 64;
    f32x4 acc[8];
#pragma unroll
    for (int ct = 0; ct < 8; ++ct) acc[ct] = (f32x4){0.f, 0.f, 0.f, 0.f};
    const _Float16* ab = Xagg + (size_t)(blk0 + wid * 16 + r) * 64 + kg * 8;
#pragma unroll
    for (int kc = 0; kc < 2; ++kc) {
        h8 a = *(const h8*)(ab + kc * 32);
#pragma unroll
        for (int ct = 0; ct < 8; ++ct) {
            h8 b = *(const h8*)(W1T + (size_t)(ct * 16 + r) * 64 + kc * 32 + kg * 8);
            acc[ct] = __builtin_amdgcn_mfma_f32_16x16x32_f16(a, b, acc[ct], 0, 0, 0);
        }
    }
#pragma unroll
    for (int ct = 0; ct < 8; ++ct) {
        float bias = b1[ct * 16 + r];
#pragma unroll
        for (int i = 0; i < 4; ++i)
            Hs[wid * 16 + 4 * kg + i][ct * 16 + r] = (_Float16)fmaxf(acc[ct][i] + bias, 0.f);
    }
    __syncthreads();
    int row = tid >> 2, q = tid & 3;
    const int4* srcp = (const int4*)&Hs[row][q * 32];
    int4 v0 = srcp[0], v1 = srcp[1], v2 = srcp[2], v3 = srcp[3];
    int4* dst = (int4*)(h1 + (size_t)(blk0 + row) * 128 + q * 32);
    dst[0] = v0; dst[1] = v1; dst[2] = v2; dst[3] = v3;
}

// Fused layer-2 aggregation + W2 GEMM + relu + global_max_pool. 256 thr = 4 waves x 16 nodes.
// Lanes (r,kg): aggregate Y[r] = di*(di*h1_r + sum_j dj*h1_j) in f32, 8-deep batched gather
// (8 recs loaded, then per kc-quarter 8 independent 16B h1 loads + FMAs -> deep MLP).
// Lanes whose node is done are exec-masked (no wasted loads). Then 32 MFMA vs W2T, +b2,
// relu, max-pool via LDS slots (block = 64 sorted nodes -> <=8 graphs) + global atomics.
#define SLOTS 8
__global__ __launch_bounds__(256) void k_aggpool(const _Float16* __restrict__ h1,
                                                 const int* __restrict__ batch,
                                                 const float* __restrict__ dinv,
                                                 const int* __restrict__ rs,
                                                 const int4* __restrict__ rec,
                                                 const _Float16* __restrict__ W2T,
                                                 const float* __restrict__ b2,
                                                 float* __restrict__ pool, int N) {
    __shared__ int lpool[SLOTS][128];
    int tid = threadIdx.x;
    for (int i = tid; i < SLOTS * 128; i += 256) ((int*)lpool)[i] = 0;
    __syncthreads();
    int l = tid & 63, wid = tid >> 6;
    int r = l & 15, kg = l >> 4;
    int blk0 = blockIdx.x * 64;
    int gfirst = batch[blk0 < N ? blk0 : N - 1];
    int base = blk0 + wid * 16;
    int noder = base + r;
    if (noder >= N) noder = N - 1;
    int e0 = rs[noder], e1 = rs[noder + 1];
    float di = dinv[noder];
    float y[32];
    {
        const _Float16* sp = h1 + (size_t)noder * 128 + kg * 8;
        // self term: init di*h1_i; final *di gives di^2*h1_i (z = di*(di*h1_i + sum))
#pragma unroll
        for (int kc = 0; kc < 4; ++kc) {
            h8 s = *(const h8*)(sp + kc * 32);
#pragma unroll
            for (int j = 0; j < 8; ++j) y[kc * 8 + j] = di * (float)s[j];
        }
    }
    // 8-deep batched edge loop; within-batch clamp dupes are weight-0 masked.
    for (int eb = e0; eb < e1; eb += 8) {
        int idx[8];
        float w[8];
#pragma unroll
        for (int i = 0; i < 8; ++i) {
            int ei = eb + i;
            int ec = (ei < e1) ? ei : e1 - 1;
            int4 rc = rec[ec];
            idx[i] = rc.z;
            w[i] = (ei < e1) ? __int_as_float(rc.y) : 0.f;
        }
#pragma unroll
        for (int kc = 0; kc < 4; ++kc) {
            h8 t[8];
#pragma unroll
            for (int i = 0; i < 8; ++i)
                t[i] = *(const h8*)(h1 + (size_t)idx[i] * 128 + kg * 8 + kc * 32);
#pragma unroll
            for (int i = 0; i < 8; ++i)
#pragma unroll
                for (int j = 0; j < 8; ++j)
                    y[kc * 8 + j] = fmaf(w[i], (float)t[i][j], y[kc * 8 + j]);
        }
    }
    // Y *= di, convert to fp16 A-fragments
    h8 af[4];
#pragma unroll
    for (int kc = 0; kc < 4; ++kc)
#pragma unroll
        for (int j = 0; j < 8; ++j) af[kc][j] = (_Float16)(di * y[kc * 8 + j]);
    // z = Y @ W2
    f32x4 acc[8];
#pragma unroll
    for (int ct = 0; ct < 8; ++ct) acc[ct] = (f32x4){0.f, 0.f, 0.f, 0.f};
#pragma unroll
    for (int kc = 0; kc < 4; ++kc) {
#pragma unroll
        for (int ct = 0; ct < 8; ++ct) {
            h8 b = *(const h8*)(W2T + (size_t)(ct * 16 + r) * 128 + kc * 32 + kg * 8);
            acc[ct] = __builtin_amdgcn_mfma_f32_16x16x32_f16(af[kc], b, acc[ct], 0, 0, 0);
        }
    }
    // bias + relu + pool (output rows of MFMA are 4*kg+i, cols ct*16+r)
    int gs[4];
#pragma unroll
    for (int i = 0; i < 4; ++i) {
        int nd = base + 4 * kg + i;
        gs[i] = (nd < N) ? batch[nd] : -1;
    }
#pragma unroll
    for (int ct = 0; ct < 8; ++ct) {
        float bias = b2[ct * 16 + r];
#pragma unroll
        for (int i = 0; i < 4; ++i) {
            if (gs[i] >= 0) {
                float z = acc[ct][i] + bias;
                if (z > 0.f) {
                    int slot = gs[i] - gfirst;
                    int col = ct * 16 + r;
                    if (slot < SLOTS)
                        atomicMax(&lpool[slot][col], __float_as_int(z));
                    else
                        atomicMax((int*)&pool[(size_t)gs[i] * 128 + col], __float_as_int(z));
                }
            }
        }
    }
    __syncthreads();
    for (int i = tid; i < SLOTS * 128; i += 256) {
        int v = ((int*)lpool)[i];
        if (v > 0) atomicMax((int*)&pool[(size_t)(gfirst + (i >> 7)) * 128 + (i & 127)], v);
    }
}

// out[g][c] = blin[c] + sum_f pool[g][f] * Wlin[f][c]
__global__ __launch_bounds__(256) void k_final(const float* __restrict__ pool, const float* __restrict__ Wlin,
                                               const float* __restrict__ blin, float* __restrict__ out, int G) {
    int t = blockIdx.x * 256 + threadIdx.x;
    if (t >= G * 10) return;
    int g = t / 10, c = t % 10;
    float acc = blin[c];
    const float* pr = pool + (size_t)g * 128;
#pragma unroll 8
    for (int f = 0; f < 128; ++f) acc = fmaf(pr[f], Wlin[f * 10 + c], acc);
    out[t] = acc;
}

extern "C" void kernel_launch(void* const* d_in, const int* in_sizes, int n_in,
                              void* d_out, int out_size, void* d_ws, size_t ws_size,
                              hipStream_t stream) {
    const int* x = (const int*)d_in[0];
    const int* ei = (const int*)d_in[1];
    const int* batch = (const int*)d_in[2];
    const float* emb = (const float*)d_in[4];
    const float* W1 = (const float*)d_in[5];
    const float* b1 = (const float*)d_in[6];
    const float* W2 = (const float*)d_in[7];
    const float* b2 = (const float*)d_in[8];
    const float* Wlin = (const float*)d_in[9];
    const float* blin = (const float*)d_in[10];
    float* out = (float*)d_out;

    int N = in_sizes[0];
    int E = in_sizes[1] / 2;
    int VOCAB = in_sizes[4] / 64;
    int G = out_size / 10;
    const int* srcp = ei;
    const int* dstp = ei + E;

    char* p = (char*)d_ws;
    auto alloc = [&](size_t bytes) -> char* {
        char* r = p;
        p += (bytes + 255) & ~(size_t)255;
        return r;
    };
    int Npad = (N + 63) & ~63;
    int* deg = (int*)alloc((size_t)N * 4);
    int* cursor = (int*)alloc((size_t)N * 4);
    int* rowstart = (int*)alloc((size_t)(N + 1) * 4);
    int* bsums = (int*)alloc(512 * 4);
    float* dinv = (float*)alloc((size_t)N * 4);
    int4* rec = (int4*)alloc((size_t)E * 16);
    _Float16* e16 = (_Float16*)alloc((size_t)VOCAB * 64 * 2);
    _Float16* W1T = (_Float16*)alloc(128 * 64 * 2);
    _Float16* W2T = (_Float16*)alloc(128 * 128 * 2);
    _Float16* Xagg = (_Float16*)alloc((size_t)Npad * 64 * 2);
    _Float16* h1 = (_Float16*)alloc((size_t)Npad * 128 * 2);
    float* pool = (float*)alloc((size_t)G * 128 * 4);

    int gE = (E + 255) / 256;
    int gN = (N + 255) / 256;  // 391 <= 512 (scan2 capacity)
    int nEmbF = VOCAB * 64;
    int nCast = (nEmbF / 4 + 255) / 256;

    int n4i = N / 4, p4i = G * 128 / 4;
    int x4i = (Npad - N) * 64 * 2 / 16;  // Xagg pad rows in int4s
    int zmax = n4i > p4i ? n4i : p4i;
    k_zero<<<(zmax + 255) / 256, 256, 0, stream>>>((int4*)deg, n4i, (int4*)pool, p4i,
                                                   (int4*)(Xagg + (size_t)N * 64), x4i);
    k_degprep<<<gE + nCast + 32 + 64, 256, 0, stream>>>(dstp, deg, E, emb, (__half2*)e16, W1, W1T,
                                                        W2, W2T, nEmbF, gE, nCast);
    k_scan1<<<gN, 256, 0, stream>>>(deg, rowstart, bsums, dinv, N);
    k_scan2<<<1, 512, 0, stream>>>(bsums, gN);
    k_scan3<<<gN, 256, 0, stream>>>(rowstart, cursor, bsums, N, E);
    k_fill<<<gE, 256, 0, stream>>>(srcp, dstp, x, dinv, cursor, rec, E);
    k_agge<<<(N + 15) / 16, 256, 0, stream>>>((const __half2*)e16, x, dinv, rowstart, rec,
                                              (__half2*)Xagg, N);
    k_gemm1<<<Npad / 64, 256, 0, stream>>>(Xagg, W1T, b1, h1, Npad);
    k_aggpool<<<(N + 63) / 64, 256, 0, stream>>>(h1, batch, dinv, rowstart, rec, W2T, b2, pool, N);
    k_final<<<(G * 10 + 255) / 256, 256, 0, stream>>>(pool, Wlin, blin, out, G);
}

// Round 15
// 228.105 us; speedup vs baseline: 1.0092x; 1.0092x over previous
//
#include <hip/hip_runtime.h>
#include <hip/hip_bf16.h>
#include <hip/hip_fp16.h>

// GCN forward: emb-gather -> GCNConv(64->128) -> ReLU -> GCNConv(128->128) -> ReLU
//              -> global_max_pool -> Linear(128->10)
// N=100000, E=600000, VOCAB=5000, G=2000, C=10.
// Layer-1 agg in 64-dim embedding space (linearity) -> gemm1 -> h1 fp16.
// Layer-2 fused kernel, two phases: (A) proven agg2pool gather schedule (half-wave per
// 2 nodes, 16-deep, a[4] f32/lane) -> Y rows in LDS fp16; (B) MFMA vs W2T + bias + relu
// + max-pool. P is never materialized.

typedef _Float16 h8 __attribute__((ext_vector_type(8)));
typedef _Float16 h4v __attribute__((ext_vector_type(4)));
typedef float f32x4 __attribute__((ext_vector_type(4)));

// Zero deg, pool, Xagg pad rows.
__global__ __launch_bounds__(256) void k_zero(int4* __restrict__ deg4, int n4i,
                                              int4* __restrict__ pool4, int p4i,
                                              int4* __restrict__ xpad, int x4i) {
    int t = blockIdx.x * 256 + threadIdx.x;
    int4 z = make_int4(0, 0, 0, 0);
    if (t < n4i) deg4[t] = z;
    if (t < p4i) pool4[t] = z;
    if (t < x4i) xpad[t] = z;
}

// Fused: [0,gE) degree atomics; [gE,gE+nCast) e16 = fp16(emb); then W1T; then W2T.
__global__ __launch_bounds__(256) void k_degprep(const int* __restrict__ dst, int* __restrict__ deg, int E,
                                                 const float* __restrict__ emb, __half2* __restrict__ e16,
                                                 const float* __restrict__ W1, _Float16* __restrict__ W1T,
                                                 const float* __restrict__ W2, _Float16* __restrict__ W2T,
                                                 int nEmbF, int gE, int nCast) {
    int bid = blockIdx.x;
    if (bid < gE) {
        int e = bid * 256 + threadIdx.x;
        if (e < E) atomicAdd(&deg[dst[e]], 1);
    } else if (bid < gE + nCast) {
        int t = (bid - gE) * 256 + threadIdx.x;  // one thread = 4 floats
        if (t * 4 < nEmbF) {
            float4 v = *(const float4*)&emb[t * 4];
            e16[t * 2] = __floats2half2_rn(v.x, v.y);
            e16[t * 2 + 1] = __floats2half2_rn(v.z, v.w);
        }
    } else if (bid < gE + nCast + 32) {
        int t = (bid - gE - nCast) * 256 + threadIdx.x;  // 128*64
        int c = t >> 6, k = t & 63;
        W1T[c * 64 + k] = (_Float16)W1[k * 128 + c];
    } else {
        int t = (bid - gE - nCast - 32) * 256 + threadIdx.x;  // 128*128
        if (t < 128 * 128) {
            int c = t >> 7, k = t & 127;
            W2T[c * 128 + k] = (_Float16)W2[k * 128 + c];
        }
    }
}

// scan1 + dinv fused
__global__ __launch_bounds__(256) void k_scan1(const int* __restrict__ deg, int* __restrict__ exc,
                                               int* __restrict__ bsums, float* __restrict__ dinv, int N) {
    __shared__ int s[256];
    int i = blockIdx.x * 256 + threadIdx.x;
    int v = (i < N) ? deg[i] : 0;
    if (i < N) dinv[i] = rsqrtf((float)(v + 1));  // +1 self-loop
    s[threadIdx.x] = v;
    __syncthreads();
    for (int off = 1; off < 256; off <<= 1) {
        int t = (threadIdx.x >= (unsigned)off) ? s[threadIdx.x - off] : 0;
        __syncthreads();
        s[threadIdx.x] += t;
        __syncthreads();
    }
    if (i < N) exc[i] = s[threadIdx.x] - v;
    if (threadIdx.x == 255) bsums[blockIdx.x] = s[255];
}

__global__ __launch_bounds__(512) void k_scan2(int* __restrict__ bsums, int nb) {
    __shared__ int s[512];
    int i = threadIdx.x;
    int v = (i < nb) ? bsums[i] : 0;
    s[i] = v;
    __syncthreads();
    for (int off = 1; off < 512; off <<= 1) {
        int t = (i >= off) ? s[i - off] : 0;
        __syncthreads();
        s[i] += t;
        __syncthreads();
    }
    if (i < nb) bsums[i] = s[i] - v;
}

__global__ __launch_bounds__(256) void k_scan3(int* __restrict__ rowstart, int* __restrict__ cursor,
                                               const int* __restrict__ bsums, int N, int E) {
    int i = blockIdx.x * 256 + threadIdx.x;
    if (i < N) {
        int r = rowstart[i] + bsums[blockIdx.x];
        rowstart[i] = r;
        cursor[i] = r;
    }
    if (i == 0 && blockIdx.x == 0) rowstart[N] = E;
}

// CSR fill: rec[pos] = {x[src], dinv[src] bits, src, 0} — ONE 16B scattered store.
__global__ __launch_bounds__(256) void k_fill(const int* __restrict__ src, const int* __restrict__ dst,
                                              const int* __restrict__ x, const float* __restrict__ dinv,
                                              int* __restrict__ cursor, int4* __restrict__ rec, int E) {
    int e = blockIdx.x * 256 + threadIdx.x;
    if (e < E) {
        int d = dst[e];
        int s = src[e];
        int pos = atomicAdd(&cursor[d], 1);
        rec[pos] = make_int4(x[s], __float_as_int(dinv[s]), s, 0);
    }
}

// 64-dim embedding-space aggregation: Xagg[i] = di*(di*e16[x_i] + sum dj*e16[x_j]).
// 256 thr = 8 half-waves x 2 nodes; dual 8-deep clamped gather batches.
__global__ __launch_bounds__(256) void k_agge(const __half2* __restrict__ e16, const int* __restrict__ x,
                                              const float* __restrict__ dinv, const int* __restrict__ rs,
                                              const int4* __restrict__ rec, __half2* __restrict__ Xagg, int N) {
    int lane = threadIdx.x & 31;
    int n0 = (blockIdx.x * 8 + (threadIdx.x >> 5)) * 2;
    if (n0 >= N) return;
    int nB = (n0 + 1 < N) ? n0 + 1 : n0;
    int cA0 = rs[n0], cA1 = rs[n0 + 1];
    int cB0 = rs[nB], cB1 = rs[nB + 1];
    bool hasA = cA0 < cA1, hasB = cB0 < cB1;
    __half2 tA[8], tB[8];
    float wA[8], wB[8];
#pragma unroll
    for (int i = 0; i < 8; ++i) {
        int ei = cA0 + i;
        int ec = (ei < cA1) ? ei : (hasA ? cA1 - 1 : 0);
        int4 r2 = rec[ec];
        tA[i] = e16[(size_t)r2.x * 32 + lane];
        wA[i] = (ei < cA1) ? __int_as_float(r2.y) : 0.f;
    }
#pragma unroll
    for (int i = 0; i < 8; ++i) {
        int ei = cB0 + i;
        int ec = (ei < cB1) ? ei : (hasB ? cB1 - 1 : 0);
        int4 r2 = rec[ec];
        tB[i] = e16[(size_t)r2.x * 32 + lane];
        wB[i] = (ei < cB1) ? __int_as_float(r2.y) : 0.f;
    }
    float dA = dinv[n0], dB = dinv[nB];
    float2 sA = __half22float2(e16[(size_t)x[n0] * 32 + lane]);
    float2 sB = __half22float2(e16[(size_t)x[nB] * 32 + lane]);
    float aA0 = dA * sA.x, aA1 = dA * sA.y;
    float aB0 = dB * sB.x, aB1 = dB * sB.y;
#pragma unroll
    for (int i = 0; i < 8; ++i) {
        float2 tf = __half22float2(tA[i]);
        aA0 = fmaf(wA[i], tf.x, aA0);
        aA1 = fmaf(wA[i], tf.y, aA1);
    }
#pragma unroll
    for (int i = 0; i < 8; ++i) {
        float2 tf = __half22float2(tB[i]);
        aB0 = fmaf(wB[i], tf.x, aB0);
        aB1 = fmaf(wB[i], tf.y, aB1);
    }
    for (int e = cA0 + 8; e < cA1; e += 8) {
#pragma unroll
        for (int i = 0; i < 8; ++i) {
            int ei = e + i;
            int ec = (ei < cA1) ? ei : cA1 - 1;
            int4 r2 = rec[ec];
            tA[i] = e16[(size_t)r2.x * 32 + lane];
            wA[i] = (ei < cA1) ? __int_as_float(r2.y) : 0.f;
        }
#pragma unroll
        for (int i = 0; i < 8; ++i) {
            float2 tf = __half22float2(tA[i]);
            aA0 = fmaf(wA[i], tf.x, aA0);
            aA1 = fmaf(wA[i], tf.y, aA1);
        }
    }
    for (int e = cB0 + 8; e < cB1; e += 8) {
#pragma unroll
        for (int i = 0; i < 8; ++i) {
            int ei = e + i;
            int ec = (ei < cB1) ? ei : cB1 - 1;
            int4 r2 = rec[ec];
            tB[i] = e16[(size_t)r2.x * 32 + lane];
            wB[i] = (ei < cB1) ? __int_as_float(r2.y) : 0.f;
        }
#pragma unroll
        for (int i = 0; i < 8; ++i) {
            float2 tf = __half22float2(tB[i]);
            aB0 = fmaf(wB[i], tf.x, aB0);
            aB1 = fmaf(wB[i], tf.y, aB1);
        }
    }
    Xagg[(size_t)n0 * 32 + lane] = __floats2half2_rn(dA * aA0, dA * aA1);
    Xagg[(size_t)nB * 32 + lane] = __floats2half2_rn(dB * aB0, dB * aB1);
}

// h1 = relu(Xagg @ W1 + b1). 256 thr = 4 waves x 16 rows, block = 64 rows.
// Stores vectorized via LDS restage (4x16B per thread, coalesced).
__global__ __launch_bounds__(256) void k_gemm1(const _Float16* __restrict__ Xagg,
                                               const _Float16* __restrict__ W1T,
                                               const float* __restrict__ b1,
                                               _Float16* __restrict__ h1, int Npad) {
    __shared__ _Float16 Hs[64][136];
    int tid = threadIdx.x;
    int l = tid & 63, wid = tid >> 6;
    int r = l & 15, kg = l >> 4;
    int blk0 = blockIdx.x * 64;
    f32x4 acc[8];
#pragma unroll
    for (int ct = 0; ct < 8; ++ct) acc[ct] = (f32x4){0.f, 0.f, 0.f, 0.f};
    const _Float16* ab = Xagg + (size_t)(blk0 + wid * 16 + r) * 64 + kg * 8;
#pragma unroll
    for (int kc = 0; kc < 2; ++kc) {
        h8 a = *(const h8*)(ab + kc * 32);
#pragma unroll
        for (int ct = 0; ct < 8; ++ct) {
            h8 b = *(const h8*)(W1T + (size_t)(ct * 16 + r) * 64 + kc * 32 + kg * 8);
            acc[ct] = __builtin_amdgcn_mfma_f32_16x16x32_f16(a, b, acc[ct], 0, 0, 0);
        }
    }
#pragma unroll
    for (int ct = 0; ct < 8; ++ct) {
        float bias = b1[ct * 16 + r];
#pragma unroll
        for (int i = 0; i < 4; ++i)
            Hs[wid * 16 + 4 * kg + i][ct * 16 + r] = (_Float16)fmaxf(acc[ct][i] + bias, 0.f);
    }
    __syncthreads();
    int row = tid >> 2, q = tid & 3;
    const int4* srcp = (const int4*)&Hs[row][q * 32];
    int4 v0 = srcp[0], v1 = srcp[1], v2 = srcp[2], v3 = srcp[3];
    int4* dst = (int4*)(h1 + (size_t)(blk0 + row) * 128 + q * 32);
    dst[0] = v0; dst[1] = v1; dst[2] = v2; dst[3] = v3;
}

// Fused layer-2: Phase A = proven agg2pool gather (16 half-waves x 2 nodes, 16-deep,
// a[4] f32/lane) -> Ys fp16 in LDS. Phase B = 8 waves MFMA vs W2T + bias + relu +
// max-pool (LDS slots + global atomics). Block = 32 sorted nodes, 512 threads.
#define SLOTS 8
__global__ __launch_bounds__(512) void k_aggpool(const _Float16* __restrict__ h1,
                                                 const int* __restrict__ batch,
                                                 const float* __restrict__ dinv,
                                                 const int* __restrict__ rs,
                                                 const int4* __restrict__ rec,
                                                 const _Float16* __restrict__ W2T,
                                                 const float* __restrict__ b2,
                                                 float* __restrict__ pool, int N) {
    __shared__ _Float16 Ys[32][136];
    __shared__ int lpool[SLOTS][128];
    int tid = threadIdx.x;
    for (int i = tid; i < SLOTS * 128; i += 512) ((int*)lpool)[i] = 0;
    int blk0 = blockIdx.x * 32;
    const h4v* H4 = (const h4v*)h1;
    // ---- Phase A: gather Y rows (proven schedule) ----
    {
        int lane = tid & 31;
        int hw = tid >> 5;  // 0..15
        int nl = hw * 2;
        int nA = blk0 + nl;     if (nA >= N) nA = N - 1;
        int nB = blk0 + nl + 1; if (nB >= N) nB = N - 1;
        int cA0 = rs[nA], cA1 = rs[nA + 1];
        int cB0 = rs[nB], cB1 = rs[nB + 1];
        bool hasA = cA0 < cA1, hasB = cB0 < cB1;
        h4v sA = H4[(size_t)nA * 32 + lane];
        h4v sB = H4[(size_t)nB * 32 + lane];
        float dA = dinv[nA], dB = dinv[nB];
        float aA[4], aB[4];
#pragma unroll
        for (int f = 0; f < 4; ++f) {
            aA[f] = dA * (float)sA[f];
            aB[f] = dB * (float)sB[f];
        }
        {
            h4v tA[16], tB[16];
            float wA[16], wB[16];
#pragma unroll
            for (int i = 0; i < 16; ++i) {
                int ei = cA0 + i;
                int ec = (ei < cA1) ? ei : (hasA ? cA1 - 1 : 0);
                int4 rc = rec[ec];
                tA[i] = H4[(size_t)rc.z * 32 + lane];
                wA[i] = (ei < cA1) ? __int_as_float(rc.y) : 0.f;
            }
#pragma unroll
            for (int i = 0; i < 16; ++i) {
                int ei = cB0 + i;
                int ec = (ei < cB1) ? ei : (hasB ? cB1 - 1 : 0);
                int4 rc = rec[ec];
                tB[i] = H4[(size_t)rc.z * 32 + lane];
                wB[i] = (ei < cB1) ? __int_as_float(rc.y) : 0.f;
            }
#pragma unroll
            for (int i = 0; i < 16; ++i)
#pragma unroll
                for (int f = 0; f < 4; ++f) aA[f] = fmaf(wA[i], (float)tA[i][f], aA[f]);
#pragma unroll
            for (int i = 0; i < 16; ++i)
#pragma unroll
                for (int f = 0; f < 4; ++f) aB[f] = fmaf(wB[i], (float)tB[i][f], aB[f]);
        }
        for (int e = cA0 + 16; e < cA1; e += 16) {
            h4v t[16];
            float w[16];
#pragma unroll
            for (int i = 0; i < 16; ++i) {
                int ei = e + i;
                int ec = (ei < cA1) ? ei : cA1 - 1;
                int4 rc = rec[ec];
                t[i] = H4[(size_t)rc.z * 32 + lane];
                w[i] = (ei < cA1) ? __int_as_float(rc.y) : 0.f;
            }
#pragma unroll
            for (int i = 0; i < 16; ++i)
#pragma unroll
                for (int f = 0; f < 4; ++f) aA[f] = fmaf(w[i], (float)t[i][f], aA[f]);
        }
        for (int e = cB0 + 16; e < cB1; e += 16) {
            h4v t[16];
            float w[16];
#pragma unroll
            for (int i = 0; i < 16; ++i) {
                int ei = e + i;
                int ec = (ei < cB1) ? ei : cB1 - 1;
                int4 rc = rec[ec];
                t[i] = H4[(size_t)rc.z * 32 + lane];
                w[i] = (ei < cB1) ? __int_as_float(rc.y) : 0.f;
            }
#pragma unroll
            for (int i = 0; i < 16; ++i)
#pragma unroll
                for (int f = 0; f < 4; ++f) aB[f] = fmaf(w[i], (float)t[i][f], aB[f]);
        }
        h4v yA, yB;
#pragma unroll
        for (int f = 0; f < 4; ++f) {
            yA[f] = (_Float16)(dA * aA[f]);
            yB[f] = (_Float16)(dB * aB[f]);
        }
        *(h4v*)&Ys[nl][lane * 4] = yA;
        *(h4v*)&Ys[nl + 1][lane * 4] = yB;
    }
    __syncthreads();
    // ---- Phase B: z = Y @ W2 + b2, relu, max-pool ----
    int l = tid & 63, wid = tid >> 6;  // 8 waves
    int r = l & 15, kg = l >> 4;
    int rt = wid & 1;    // row tile (16 rows)
    int colq = wid >> 1; // col quarter (32 cols)
    h8 af[4];
#pragma unroll
    for (int kc = 0; kc < 4; ++kc) af[kc] = *(const h8*)&Ys[rt * 16 + r][kc * 32 + kg * 8];
    f32x4 acc[2];
#pragma unroll
    for (int ct = 0; ct < 2; ++ct) acc[ct] = (f32x4){0.f, 0.f, 0.f, 0.f};
#pragma unroll
    for (int kc = 0; kc < 4; ++kc) {
#pragma unroll
        for (int ct = 0; ct < 2; ++ct) {
            h8 b = *(const h8*)(W2T + (size_t)(colq * 32 + ct * 16 + r) * 128 + kc * 32 + kg * 8);
            acc[ct] = __builtin_amdgcn_mfma_f32_16x16x32_f16(af[kc], b, acc[ct], 0, 0, 0);
        }
    }
    int gfirst = batch[blk0 < N ? blk0 : N - 1];
    int gs[4];
#pragma unroll
    for (int i = 0; i < 4; ++i) {
        int nd = blk0 + rt * 16 + 4 * kg + i;
        gs[i] = (nd < N) ? batch[nd] : -1;
    }
#pragma unroll
    for (int ct = 0; ct < 2; ++ct) {
        int col = colq * 32 + ct * 16 + r;
        float bias = b2[col];
#pragma unroll
        for (int i = 0; i < 4; ++i) {
            if (gs[i] >= 0) {
                float z = acc[ct][i] + bias;
                if (z > 0.f) {
                    int slot = gs[i] - gfirst;
                    if (slot < SLOTS)
                        atomicMax(&lpool[slot][col], __float_as_int(z));
                    else
                        atomicMax((int*)&pool[(size_t)gs[i] * 128 + col], __float_as_int(z));
                }
            }
        }
    }
    __syncthreads();
    for (int i = tid; i < SLOTS * 128; i += 512) {
        int v = ((int*)lpool)[i];
        if (v > 0) atomicMax((int*)&pool[(size_t)(gfirst + (i >> 7)) * 128 + (i & 127)], v);
    }
}

// out[g][c] = blin[c] + sum_f pool[g][f] * Wlin[f][c]
__global__ __launch_bounds__(256) void k_final(const float* __restrict__ pool, const float* __restrict__ Wlin,
                                               const float* __restrict__ blin, float* __restrict__ out, int G) {
    int t = blockIdx.x * 256 + threadIdx.x;
    if (t >= G * 10) return;
    int g = t / 10, c = t % 10;
    float acc = blin[c];
    const float* pr = pool + (size_t)g * 128;
#pragma unroll 8
    for (int f = 0; f < 128; ++f) acc = fmaf(pr[f], Wlin[f * 10 + c], acc);
    out[t] = acc;
}

extern "C" void kernel_launch(void* const* d_in, const int* in_sizes, int n_in,
                              void* d_out, int out_size, void* d_ws, size_t ws_size,
                              hipStream_t stream) {
    const int* x = (const int*)d_in[0];
    const int* ei = (const int*)d_in[1];
    const int* batch = (const int*)d_in[2];
    const float* emb = (const float*)d_in[4];
    const float* W1 = (const float*)d_in[5];
    const float* b1 = (const float*)d_in[6];
    const float* W2 = (const float*)d_in[7];
    const float* b2 = (const float*)d_in[8];
    const float* Wlin = (const float*)d_in[9];
    const float* blin = (const float*)d_in[10];
    float* out = (float*)d_out;

    int N = in_sizes[0];
    int E = in_sizes[1] / 2;
    int VOCAB = in_sizes[4] / 64;
    int G = out_size / 10;
    const int* srcp = ei;
    const int* dstp = ei + E;

    char* p = (char*)d_ws;
    auto alloc = [&](size_t bytes) -> char* {
        char* r = p;
        p += (bytes + 255) & ~(size_t)255;
        return r;
    };
    int Npad = (N + 63) & ~63;
    int* deg = (int*)alloc((size_t)N * 4);
    int* cursor = (int*)alloc((size_t)N * 4);
    int* rowstart = (int*)alloc((size_t)(N + 1) * 4);
    int* bsums = (int*)alloc(512 * 4);
    float* dinv = (float*)alloc((size_t)N * 4);
    int4* rec = (int4*)alloc((size_t)E * 16);
    _Float16* e16 = (_Float16*)alloc((size_t)VOCAB * 64 * 2);
    _Float16* W1T = (_Float16*)alloc(128 * 64 * 2);
    _Float16* W2T = (_Float16*)alloc(128 * 128 * 2);
    _Float16* Xagg = (_Float16*)alloc((size_t)Npad * 64 * 2);
    _Float16* h1 = (_Float16*)alloc((size_t)Npad * 128 * 2);
    float* pool = (float*)alloc((size_t)G * 128 * 4);

    int gE = (E + 255) / 256;
    int gN = (N + 255) / 256;  // 391 <= 512 (scan2 capacity)
    int nEmbF = VOCAB * 64;
    int nCast = (nEmbF / 4 + 255) / 256;

    int n4i = N / 4, p4i = G * 128 / 4;
    int x4i = (Npad - N) * 64 * 2 / 16;  // Xagg pad rows in int4s
    int zmax = n4i > p4i ? n4i : p4i;
    k_zero<<<(zmax + 255) / 256, 256, 0, stream>>>((int4*)deg, n4i, (int4*)pool, p4i,
                                                   (int4*)(Xagg + (size_t)N * 64), x4i);
    k_degprep<<<gE + nCast + 32 + 64, 256, 0, stream>>>(dstp, deg, E, emb, (__half2*)e16, W1, W1T,
                                                        W2, W2T, nEmbF, gE, nCast);
    k_scan1<<<gN, 256, 0, stream>>>(deg, rowstart, bsums, dinv, N);
    k_scan2<<<1, 512, 0, stream>>>(bsums, gN);
    k_scan3<<<gN, 256, 0, stream>>>(rowstart, cursor, bsums, N, E);
    k_fill<<<gE, 256, 0, stream>>>(srcp, dstp, x, dinv, cursor, rec, E);
    k_agge<<<(N + 15) / 16, 256, 0, stream>>>((const __half2*)e16, x, dinv, rowstart, rec,
                                              (__half2*)Xagg, N);
    k_gemm1<<<Npad / 64, 256, 0, stream>>>(Xagg, W1T, b1, h1, Npad);
    k_aggpool<<<(N + 31) / 32, 512, 0, stream>>>(h1, batch, dinv, rowstart, rec, W2T, b2, pool, N);
    k_final<<<(G * 10 + 255) / 256, 256, 0, stream>>>(pool, Wlin, blin, out, G);
}

// Round 16
// 185.775 us; speedup vs baseline: 1.2391x; 1.2279x over previous
//
#include <hip/hip_runtime.h>
#include <hip/hip_bf16.h>
#include <hip/hip_fp16.h>

// GCN forward: emb-gather -> GCNConv(64->128) -> ReLU -> GCNConv(128->128) -> ReLU
//              -> global_max_pool -> Linear(128->10)
// N=100000, E=600000, VOCAB=5000, G=2000, C=10.
// k_mlp (512 thr / 64 nodes): phase 1 aggregates 64-dim embeddings with 16B/lane
// quad-row gathers (lane=(quad,slot); one load covers 4 edge rows; shfl_xor reduce),
// then 8-wave MFMA gemm1(+bias,relu) -> LDS -> gemm2(dinv) -> P fp16.
// k_agg2pool: proven 256-thr 16-deep dual gather + LDS pool consolidation.

typedef _Float16 h8 __attribute__((ext_vector_type(8)));
typedef _Float16 h4v __attribute__((ext_vector_type(4)));
typedef float f32x4 __attribute__((ext_vector_type(4)));

// Zero deg (n4i int4s) and pool (p4i int4s).
__global__ __launch_bounds__(256) void k_zero(int4* __restrict__ deg, int n4i,
                                              int4* __restrict__ pool, int p4i) {
    int t = blockIdx.x * 256 + threadIdx.x;
    int4 z = make_int4(0, 0, 0, 0);
    if (t < n4i) deg[t] = z;
    if (t < p4i) pool[t] = z;
}

// Fused: [0,gE) degree atomics; [gE,gE+nCast) e16 = fp16(emb); then W1T; then W2T.
__global__ __launch_bounds__(256) void k_degprep(const int* __restrict__ dst, int* __restrict__ deg, int E,
                                                 const float* __restrict__ emb, __half2* __restrict__ e16,
                                                 const float* __restrict__ W1, _Float16* __restrict__ W1T,
                                                 const float* __restrict__ W2, _Float16* __restrict__ W2T,
                                                 int nEmbF, int gE, int nCast) {
    int bid = blockIdx.x;
    if (bid < gE) {
        int e = bid * 256 + threadIdx.x;
        if (e < E) atomicAdd(&deg[dst[e]], 1);
    } else if (bid < gE + nCast) {
        int t = (bid - gE) * 256 + threadIdx.x;  // one thread = 4 floats
        if (t * 4 < nEmbF) {
            float4 v = *(const float4*)&emb[t * 4];
            e16[t * 2] = __floats2half2_rn(v.x, v.y);
            e16[t * 2 + 1] = __floats2half2_rn(v.z, v.w);
        }
    } else if (bid < gE + nCast + 32) {
        int t = (bid - gE - nCast) * 256 + threadIdx.x;  // 128*64
        int c = t >> 6, k = t & 63;
        W1T[c * 64 + k] = (_Float16)W1[k * 128 + c];
    } else {
        int t = (bid - gE - nCast - 32) * 256 + threadIdx.x;  // 128*128
        if (t < 128 * 128) {
            int c = t >> 7, k = t & 127;
            W2T[c * 128 + k] = (_Float16)W2[k * 128 + c];
        }
    }
}

// scan1 + dinv fused
__global__ __launch_bounds__(256) void k_scan1(const int* __restrict__ deg, int* __restrict__ exc,
                                               int* __restrict__ bsums, float* __restrict__ dinv, int N) {
    __shared__ int s[256];
    int i = blockIdx.x * 256 + threadIdx.x;
    int v = (i < N) ? deg[i] : 0;
    if (i < N) dinv[i] = rsqrtf((float)(v + 1));  // +1 self-loop
    s[threadIdx.x] = v;
    __syncthreads();
    for (int off = 1; off < 256; off <<= 1) {
        int t = (threadIdx.x >= (unsigned)off) ? s[threadIdx.x - off] : 0;
        __syncthreads();
        s[threadIdx.x] += t;
        __syncthreads();
    }
    if (i < N) exc[i] = s[threadIdx.x] - v;
    if (threadIdx.x == 255) bsums[blockIdx.x] = s[255];
}

__global__ __launch_bounds__(512) void k_scan2(int* __restrict__ bsums, int nb) {
    __shared__ int s[512];
    int i = threadIdx.x;
    int v = (i < nb) ? bsums[i] : 0;
    s[i] = v;
    __syncthreads();
    for (int off = 1; off < 512; off <<= 1) {
        int t = (i >= off) ? s[i - off] : 0;
        __syncthreads();
        s[i] += t;
        __syncthreads();
    }
    if (i < nb) bsums[i] = s[i] - v;
}

__global__ __launch_bounds__(256) void k_scan3(int* __restrict__ rowstart, int* __restrict__ cursor,
                                               const int* __restrict__ bsums, int N, int E) {
    int i = blockIdx.x * 256 + threadIdx.x;
    if (i < N) {
        int r = rowstart[i] + bsums[blockIdx.x];
        rowstart[i] = r;
        cursor[i] = r;
    }
    if (i == 0 && blockIdx.x == 0) rowstart[N] = E;
}

// CSR fill: ed[pos] = {x[src], dinv[src] bits}; cols[pos] = src
__global__ __launch_bounds__(256) void k_fill(const int* __restrict__ src, const int* __restrict__ dst,
                                              const int* __restrict__ x, const float* __restrict__ dinv,
                                              int* __restrict__ cursor, int2* __restrict__ ed,
                                              int* __restrict__ cols, int E) {
    int e = blockIdx.x * 256 + threadIdx.x;
    if (e < E) {
        int d = dst[e];
        int s = src[e];
        int pos = atomicAdd(&cursor[d], 1);
        ed[pos] = make_int2(x[s], __float_as_int(dinv[s]));
        cols[pos] = s;
    }
}

// Fused node pipeline: 512 threads, block = 64 nodes.
// Phase 1: 16 half-waves x 4 nodes (2 passes x 2 nodes). Quad-row gathers: lane =
//   (p=lane>>3, f16=lane&7); each 16B load covers 4 different edge rows; per-lane edge
//   metadata; f32 accum over 8 feats; shfl_xor(8,16) reduce; p==0 lanes write Xs.
// Phase 2: Hs = relu(Xs @ W1 + b1)   (8 waves: 4 row-blocks x 2 col-halves, MFMA)
// Phase 3: P  = dinv * (Hs @ W2)     (same partition, MFMA)
__global__ __launch_bounds__(512) void k_mlp(const __half2* __restrict__ e16, const int* __restrict__ x,
                                             const float* __restrict__ dinv, const int* __restrict__ rs,
                                             const int2* __restrict__ ed, const _Float16* __restrict__ W1T,
                                             const float* __restrict__ b1, const _Float16* __restrict__ W2T,
                                             _Float16* __restrict__ P, int N) {
    __shared__ _Float16 Xs[64][72];    // 64-dim rows, stride 144B
    __shared__ _Float16 Hs[64][136];   // 128-dim rows, stride 272B
    int tid = threadIdx.x;
    int blk0 = blockIdx.x * 64;
    // ---- Phase 1 ----
    {
        int lane = tid & 31;
        int hw = tid >> 5;   // 0..15
        int p = lane >> 3;   // 0..3 quad
        int f16 = lane & 7;  // h8 slot (8 fp16 feats)
        const h8* e8 = (const h8*)e16;
#pragma unroll
        for (int pass = 0; pass < 2; ++pass) {
            int nlA = hw * 4 + pass * 2, nlB = nlA + 1;
            int gA = blk0 + nlA; if (gA >= N) gA = N - 1;
            int gB = blk0 + nlB; if (gB >= N) gB = N - 1;
            int cA0 = rs[gA], cA1 = rs[gA + 1];
            int cB0 = rs[gB], cB1 = rs[gB + 1];
            int baseA = (cA0 < cA1) ? cA1 - 1 : 0;
            int baseB = (cB0 < cB1) ? cB1 - 1 : 0;
            float dA = dinv[gA], dB = dinv[gB];
            h8 selfA = e8[(size_t)x[gA] * 8 + f16];
            h8 selfB = e8[(size_t)x[gB] * 8 + f16];
            float accA[8] = {}, accB[8] = {};
            // first batches of A and B issued together: 4 row-loads x 4 rows = 16 rows in flight
            {
                int eA0 = cA0 + p, eA1 = cA0 + 4 + p;
                int eB0 = cB0 + p, eB1 = cB0 + 4 + p;
                int2 rA0 = ed[(eA0 < cA1) ? eA0 : baseA];
                int2 rA1 = ed[(eA1 < cA1) ? eA1 : baseA];
                int2 rB0 = ed[(eB0 < cB1) ? eB0 : baseB];
                int2 rB1 = ed[(eB1 < cB1) ? eB1 : baseB];
                h8 tA0 = e8[(size_t)rA0.x * 8 + f16];
                h8 tA1 = e8[(size_t)rA1.x * 8 + f16];
                h8 tB0 = e8[(size_t)rB0.x * 8 + f16];
                h8 tB1 = e8[(size_t)rB1.x * 8 + f16];
                float wA0 = (eA0 < cA1) ? __int_as_float(rA0.y) : 0.f;
                float wA1 = (eA1 < cA1) ? __int_as_float(rA1.y) : 0.f;
                float wB0 = (eB0 < cB1) ? __int_as_float(rB0.y) : 0.f;
                float wB1 = (eB1 < cB1) ? __int_as_float(rB1.y) : 0.f;
#pragma unroll
                for (int f = 0; f < 8; ++f) {
                    accA[f] = fmaf(wA1, (float)tA1[f], fmaf(wA0, (float)tA0[f], accA[f]));
                    accB[f] = fmaf(wB1, (float)tB1[f], fmaf(wB0, (float)tB0[f], accB[f]));
                }
            }
            // tails (deg > 8)
            for (int eb = cA0 + 8; eb < cA1; eb += 8) {
                int e0 = eb + p, e1i = eb + 4 + p;
                int2 r0 = ed[(e0 < cA1) ? e0 : cA1 - 1];
                int2 r1 = ed[(e1i < cA1) ? e1i : cA1 - 1];
                h8 t0 = e8[(size_t)r0.x * 8 + f16];
                h8 t1 = e8[(size_t)r1.x * 8 + f16];
                float w0 = (e0 < cA1) ? __int_as_float(r0.y) : 0.f;
                float w1 = (e1i < cA1) ? __int_as_float(r1.y) : 0.f;
#pragma unroll
                for (int f = 0; f < 8; ++f)
                    accA[f] = fmaf(w1, (float)t1[f], fmaf(w0, (float)t0[f], accA[f]));
            }
            for (int eb = cB0 + 8; eb < cB1; eb += 8) {
                int e0 = eb + p, e1i = eb + 4 + p;
                int2 r0 = ed[(e0 < cB1) ? e0 : cB1 - 1];
                int2 r1 = ed[(e1i < cB1) ? e1i : cB1 - 1];
                h8 t0 = e8[(size_t)r0.x * 8 + f16];
                h8 t1 = e8[(size_t)r1.x * 8 + f16];
                float w0 = (e0 < cB1) ? __int_as_float(r0.y) : 0.f;
                float w1 = (e1i < cB1) ? __int_as_float(r1.y) : 0.f;
#pragma unroll
                for (int f = 0; f < 8; ++f)
                    accB[f] = fmaf(w1, (float)t1[f], fmaf(w0, (float)t0[f], accB[f]));
            }
            // cross-quad reduce (within 32-lane group) + self + scale, p==0 writes
            h8 yA, yB;
#pragma unroll
            for (int f = 0; f < 8; ++f) {
                float a = accA[f];
                a += __shfl_xor(a, 8);
                a += __shfl_xor(a, 16);
                float b = accB[f];
                b += __shfl_xor(b, 8);
                b += __shfl_xor(b, 16);
                yA[f] = (_Float16)(dA * fmaf(dA, (float)selfA[f], a));
                yB[f] = (_Float16)(dB * fmaf(dB, (float)selfB[f], b));
            }
            if (p == 0) {
                *(h8*)&Xs[nlA][f16 * 8] = yA;
                *(h8*)&Xs[nlB][f16 * 8] = yB;
            }
        }
    }
    __syncthreads();
    int l = tid & 63, wid = tid >> 6;    // 8 waves
    int r = l & 15, kg = l >> 4;
    int rb = wid & 3;                    // row block: 16 rows
    int ch = wid >> 2;                   // col half: 64 cols
    // ---- Phase 2: Hs = relu(Xs @ W1 + b1), wave = 16 rows x 64 cols ----
    {
        f32x4 acc[4];
#pragma unroll
        for (int ct = 0; ct < 4; ++ct) acc[ct] = (f32x4){0.f, 0.f, 0.f, 0.f};
#pragma unroll
        for (int kc = 0; kc < 2; ++kc) {
            h8 a = *(const h8*)&Xs[rb * 16 + r][kc * 32 + kg * 8];
#pragma unroll
            for (int ct = 0; ct < 4; ++ct) {
                h8 b = *(const h8*)(W1T + (size_t)(ch * 64 + ct * 16 + r) * 64 + kc * 32 + kg * 8);
                acc[ct] = __builtin_amdgcn_mfma_f32_16x16x32_f16(a, b, acc[ct], 0, 0, 0);
            }
        }
#pragma unroll
        for (int ct = 0; ct < 4; ++ct) {
            float bias = b1[ch * 64 + ct * 16 + r];
#pragma unroll
            for (int i = 0; i < 4; ++i)
                Hs[rb * 16 + 4 * kg + i][ch * 64 + ct * 16 + r] =
                    (_Float16)fmaxf(acc[ct][i] + bias, 0.f);
        }
    }
    __syncthreads();
    // ---- Phase 3: P = dinv * (Hs @ W2), wave = 16 rows x 64 cols ----
    {
        f32x4 acc[4];
#pragma unroll
        for (int ct = 0; ct < 4; ++ct) acc[ct] = (f32x4){0.f, 0.f, 0.f, 0.f};
#pragma unroll
        for (int kc = 0; kc < 4; ++kc) {
            h8 a = *(const h8*)&Hs[rb * 16 + r][kc * 32 + kg * 8];
#pragma unroll
            for (int ct = 0; ct < 4; ++ct) {
                h8 b = *(const h8*)(W2T + (size_t)(ch * 64 + ct * 16 + r) * 128 + kc * 32 + kg * 8);
                acc[ct] = __builtin_amdgcn_mfma_f32_16x16x32_f16(a, b, acc[ct], 0, 0, 0);
            }
        }
        float dv[4];
#pragma unroll
        for (int i = 0; i < 4; ++i) {
            int gr = blk0 + rb * 16 + 4 * kg + i;
            dv[i] = (gr < N) ? dinv[gr] : 0.f;
        }
#pragma unroll
        for (int ct = 0; ct < 4; ++ct) {
#pragma unroll
            for (int i = 0; i < 4; ++i) {
                int gr = blk0 + rb * 16 + 4 * kg + i;
                if (gr < N)
                    P[(size_t)gr * 128 + ch * 64 + ct * 16 + r] = (_Float16)(acc[ct][i] * dv[i]);
            }
        }
    }
}

// Layer-2 + global_max_pool. 256-thr block = 8 half-waves x 2 nodes = 16 sorted nodes.
// 16-deep dual-interleaved clamped gathers. LDS pool slots, one global emit per
// (block, graph, feature).
__global__ __launch_bounds__(256) void k_agg2pool(const h4v* __restrict__ P4, const int* __restrict__ batch,
                                                  const float* __restrict__ dinv, const int* __restrict__ rs,
                                                  const int* __restrict__ cols, const float4* __restrict__ bias4,
                                                  float* __restrict__ pool, int N, int G) {
    __shared__ int lpool[4][128];
    int tid = threadIdx.x;
    lpool[tid >> 7][tid & 127] = 0;
    lpool[(tid >> 7) + 2][tid & 127] = 0;
    __syncthreads();
    int lane = tid & 31;
    int blk_n0 = blockIdx.x * 16;
    int gfirst = batch[(blk_n0 < N) ? blk_n0 : (N - 1)];
    int n0 = blk_n0 + (tid >> 5) * 2;
    if (n0 < N) {
        int nA = n0;
        int nB = (n0 + 1 < N) ? n0 + 1 : n0;
        int cA0 = rs[nA], cA1 = rs[nA + 1];
        int cB0 = rs[nB], cB1 = rs[nB + 1];
        bool hasA = cA0 < cA1, hasB = cB0 < cB1;
        h4v sA = P4[(size_t)nA * 32 + lane];
        h4v sB = P4[(size_t)nB * 32 + lane];
        float aA[4], aB[4];
#pragma unroll
        for (int f = 0; f < 4; ++f) {
            aA[f] = (float)sA[f];
            aB[f] = (float)sB[f];
        }
        {
            h4v tA[16], tB[16];
#pragma unroll
            for (int i = 0; i < 16; ++i) {
                int ei = cA0 + i;
                int ec = (ei < cA1) ? ei : (hasA ? cA1 - 1 : 0);
                tA[i] = P4[(size_t)cols[ec] * 32 + lane];
            }
#pragma unroll
            for (int i = 0; i < 16; ++i) {
                int ei = cB0 + i;
                int ec = (ei < cB1) ? ei : (hasB ? cB1 - 1 : 0);
                tB[i] = P4[(size_t)cols[ec] * 32 + lane];
            }
#pragma unroll
            for (int i = 0; i < 16; ++i) {
                float w = (cA0 + i < cA1) ? 1.f : 0.f;
#pragma unroll
                for (int f = 0; f < 4; ++f) aA[f] = fmaf(w, (float)tA[i][f], aA[f]);
            }
#pragma unroll
            for (int i = 0; i < 16; ++i) {
                float w = (cB0 + i < cB1) ? 1.f : 0.f;
#pragma unroll
                for (int f = 0; f < 4; ++f) aB[f] = fmaf(w, (float)tB[i][f], aB[f]);
            }
        }
        for (int e = cA0 + 16; e < cA1; e += 16) {
            h4v t[16];
#pragma unroll
            for (int i = 0; i < 16; ++i) {
                int ei = e + i;
                int ec = (ei < cA1) ? ei : cA1 - 1;
                t[i] = P4[(size_t)cols[ec] * 32 + lane];
            }
#pragma unroll
            for (int i = 0; i < 16; ++i) {
                float w = (e + i < cA1) ? 1.f : 0.f;
#pragma unroll
                for (int f = 0; f < 4; ++f) aA[f] = fmaf(w, (float)t[i][f], aA[f]);
            }
        }
        for (int e = cB0 + 16; e < cB1; e += 16) {
            h4v t[16];
#pragma unroll
            for (int i = 0; i < 16; ++i) {
                int ei = e + i;
                int ec = (ei < cB1) ? ei : cB1 - 1;
                t[i] = P4[(size_t)cols[ec] * 32 + lane];
            }
#pragma unroll
            for (int i = 0; i < 16; ++i) {
                float w = (e + i < cB1) ? 1.f : 0.f;
#pragma unroll
                for (int f = 0; f < 4; ++f) aB[f] = fmaf(w, (float)t[i][f], aB[f]);
            }
        }
        float dA = dinv[nA], dB = dinv[nB];
        int gA = batch[nA], gB = batch[nB];
        float4 b = bias4[lane];
        float bv[4] = {b.x, b.y, b.z, b.w};
        float zA[4], zB[4];
#pragma unroll
        for (int f = 0; f < 4; ++f) {
            zA[f] = fmaxf(fmaf(dA, aA[f], bv[f]), 0.f);
            zB[f] = fmaxf(fmaf(dB, aB[f], bv[f]), 0.f);
        }
        int rot = (lane >> 3) & 3;  // bank-rotation for LDS atomics
        auto emit = [&](int g, const float* m) {
            int slot = g - gfirst;
            if (slot < 4) {
#pragma unroll
                for (int f = 0; f < 4; ++f) {
                    int ff = (f + rot) & 3;
                    if (m[ff] > 0.f) atomicMax(&lpool[slot][lane * 4 + ff], __float_as_int(m[ff]));
                }
            } else {
                float* pg = pool + (size_t)g * 128 + lane * 4;
#pragma unroll
                for (int f = 0; f < 4; ++f)
                    if (m[f] > 0.f) atomicMax((int*)(pg + f), __float_as_int(m[f]));
            }
        };
        if (gA == gB) {
            float m[4];
#pragma unroll
            for (int f = 0; f < 4; ++f) m[f] = fmaxf(zA[f], zB[f]);
            emit(gA, m);
        } else {
            emit(gA, zA);
            emit(gB, zB);
        }
    }
    __syncthreads();
    {
        int f = tid & 127;
        for (int s = tid >> 7; s < 4; s += 2) {
            int v = lpool[s][f];
            if (v > 0) atomicMax((int*)&pool[(size_t)(gfirst + s) * 128 + f], v);
        }
    }
}

// out[g][c] = blin[c] + sum_f pool[g][f] * Wlin[f][c]
__global__ __launch_bounds__(256) void k_final(const float* __restrict__ pool, const float* __restrict__ Wlin,
                                               const float* __restrict__ blin, float* __restrict__ out, int G) {
    int t = blockIdx.x * 256 + threadIdx.x;
    if (t >= G * 10) return;
    int g = t / 10, c = t % 10;
    float acc = blin[c];
    const float* pr = pool + (size_t)g * 128;
#pragma unroll 8
    for (int f = 0; f < 128; ++f) acc = fmaf(pr[f], Wlin[f * 10 + c], acc);
    out[t] = acc;
}

extern "C" void kernel_launch(void* const* d_in, const int* in_sizes, int n_in,
                              void* d_out, int out_size, void* d_ws, size_t ws_size,
                              hipStream_t stream) {
    const int* x = (const int*)d_in[0];
    const int* ei = (const int*)d_in[1];
    const int* batch = (const int*)d_in[2];
    const float* emb = (const float*)d_in[4];
    const float* W1 = (const float*)d_in[5];
    const float* b1 = (const float*)d_in[6];
    const float* W2 = (const float*)d_in[7];
    const float* b2 = (const float*)d_in[8];
    const float* Wlin = (const float*)d_in[9];
    const float* blin = (const float*)d_in[10];
    float* out = (float*)d_out;

    int N = in_sizes[0];
    int E = in_sizes[1] / 2;
    int VOCAB = in_sizes[4] / 64;
    int G = out_size / 10;
    const int* srcp = ei;
    const int* dstp = ei + E;

    char* p = (char*)d_ws;
    auto alloc = [&](size_t bytes) -> char* {
        char* r = p;
        p += (bytes + 255) & ~(size_t)255;
        return r;
    };
    int* deg = (int*)alloc((size_t)N * 4);
    int* cursor = (int*)alloc((size_t)N * 4);
    int* rowstart = (int*)alloc((size_t)(N + 1) * 4);
    int* bsums = (int*)alloc(512 * 4);
    float* dinv = (float*)alloc((size_t)N * 4);
    int2* ed = (int2*)alloc((size_t)E * 8);
    int* cols = (int*)alloc((size_t)E * 4);
    _Float16* e16 = (_Float16*)alloc((size_t)VOCAB * 64 * 2);
    _Float16* W1T = (_Float16*)alloc(128 * 64 * 2);
    _Float16* W2T = (_Float16*)alloc(128 * 128 * 2);
    _Float16* P = (_Float16*)alloc((size_t)N * 128 * 2);
    float* pool = (float*)alloc((size_t)G * 128 * 4);

    int gE = (E + 255) / 256;
    int gN = (N + 255) / 256;  // 391 <= 512 (scan2 capacity)
    int nEmbF = VOCAB * 64;
    int nCast = (nEmbF / 4 + 255) / 256;

    int n4i = N / 4, p4i = G * 128 / 4;
    int zg = ((n4i > p4i ? n4i : p4i) + 255) / 256;
    k_zero<<<zg, 256, 0, stream>>>((int4*)deg, n4i, (int4*)pool, p4i);
    k_degprep<<<gE + nCast + 32 + 64, 256, 0, stream>>>(dstp, deg, E, emb, (__half2*)e16, W1, W1T,
                                                        W2, W2T, nEmbF, gE, nCast);
    k_scan1<<<gN, 256, 0, stream>>>(deg, rowstart, bsums, dinv, N);
    k_scan2<<<1, 512, 0, stream>>>(bsums, gN);
    k_scan3<<<gN, 256, 0, stream>>>(rowstart, cursor, bsums, N, E);
    k_fill<<<gE, 256, 0, stream>>>(srcp, dstp, x, dinv, cursor, ed, cols, E);
    k_mlp<<<(N + 63) / 64, 512, 0, stream>>>((const __half2*)e16, x, dinv, rowstart, ed, W1T, b1,
                                             W2T, P, N);
    k_agg2pool<<<(N + 15) / 16, 256, 0, stream>>>((const h4v*)P, batch, dinv, rowstart, cols,
                                                  (const float4*)b2, pool, N, G);
    k_final<<<(G * 10 + 255) / 256, 256, 0, stream>>>(pool, Wlin, blin, out, G);
}

// Round 17
// 180.314 us; speedup vs baseline: 1.2766x; 1.0303x over previous
//
#include <hip/hip_runtime.h>
#include <hip/hip_bf16.h>
#include <hip/hip_fp16.h>

// GCN forward: emb-gather -> GCNConv(64->128) -> ReLU -> GCNConv(128->128) -> ReLU
//              -> global_max_pool -> Linear(128->10)
// N=100000, E=600000, VOCAB=5000, G=2000, C=10.
// k_mlp (512 thr / 32 nodes, SINGLE pass): 16 half-waves x 2 nodes; 16B/lane quad-row
// gathers (lane=(quad,slot), one load covers 4 edge rows, shfl_xor reduce) -> LDS ->
// 8-wave MFMA gemm1(+bias,relu) -> LDS -> gemm2(dinv) -> P fp16.
// k_agg2pool: 16B/lane parity gather (one load covers 2 rows), shfl_xor(16) reduce,
// LDS pool consolidation.

typedef _Float16 h8 __attribute__((ext_vector_type(8)));
typedef float f32x4 __attribute__((ext_vector_type(4)));

// Zero deg (n4i int4s) and pool (p4i int4s).
__global__ __launch_bounds__(256) void k_zero(int4* __restrict__ deg, int n4i,
                                              int4* __restrict__ pool, int p4i) {
    int t = blockIdx.x * 256 + threadIdx.x;
    int4 z = make_int4(0, 0, 0, 0);
    if (t < n4i) deg[t] = z;
    if (t < p4i) pool[t] = z;
}

// Fused: [0,gE) degree atomics; [gE,gE+nCast) e16 = fp16(emb); then W1T; then W2T.
__global__ __launch_bounds__(256) void k_degprep(const int* __restrict__ dst, int* __restrict__ deg, int E,
                                                 const float* __restrict__ emb, __half2* __restrict__ e16,
                                                 const float* __restrict__ W1, _Float16* __restrict__ W1T,
                                                 const float* __restrict__ W2, _Float16* __restrict__ W2T,
                                                 int nEmbF, int gE, int nCast) {
    int bid = blockIdx.x;
    if (bid < gE) {
        int e = bid * 256 + threadIdx.x;
        if (e < E) atomicAdd(&deg[dst[e]], 1);
    } else if (bid < gE + nCast) {
        int t = (bid - gE) * 256 + threadIdx.x;  // one thread = 4 floats
        if (t * 4 < nEmbF) {
            float4 v = *(const float4*)&emb[t * 4];
            e16[t * 2] = __floats2half2_rn(v.x, v.y);
            e16[t * 2 + 1] = __floats2half2_rn(v.z, v.w);
        }
    } else if (bid < gE + nCast + 32) {
        int t = (bid - gE - nCast) * 256 + threadIdx.x;  // 128*64
        int c = t >> 6, k = t & 63;
        W1T[c * 64 + k] = (_Float16)W1[k * 128 + c];
    } else {
        int t = (bid - gE - nCast - 32) * 256 + threadIdx.x;  // 128*128
        if (t < 128 * 128) {
            int c = t >> 7, k = t & 127;
            W2T[c * 128 + k] = (_Float16)W2[k * 128 + c];
        }
    }
}

// scan1 + dinv fused
__global__ __launch_bounds__(256) void k_scan1(const int* __restrict__ deg, int* __restrict__ exc,
                                               int* __restrict__ bsums, float* __restrict__ dinv, int N) {
    __shared__ int s[256];
    int i = blockIdx.x * 256 + threadIdx.x;
    int v = (i < N) ? deg[i] : 0;
    if (i < N) dinv[i] = rsqrtf((float)(v + 1));  // +1 self-loop
    s[threadIdx.x] = v;
    __syncthreads();
    for (int off = 1; off < 256; off <<= 1) {
        int t = (threadIdx.x >= (unsigned)off) ? s[threadIdx.x - off] : 0;
        __syncthreads();
        s[threadIdx.x] += t;
        __syncthreads();
    }
    if (i < N) exc[i] = s[threadIdx.x] - v;
    if (threadIdx.x == 255) bsums[blockIdx.x] = s[255];
}

__global__ __launch_bounds__(512) void k_scan2(int* __restrict__ bsums, int nb) {
    __shared__ int s[512];
    int i = threadIdx.x;
    int v = (i < nb) ? bsums[i] : 0;
    s[i] = v;
    __syncthreads();
    for (int off = 1; off < 512; off <<= 1) {
        int t = (i >= off) ? s[i - off] : 0;
        __syncthreads();
        s[i] += t;
        __syncthreads();
    }
    if (i < nb) bsums[i] = s[i] - v;
}

__global__ __launch_bounds__(256) void k_scan3(int* __restrict__ rowstart, int* __restrict__ cursor,
                                               const int* __restrict__ bsums, int N, int E) {
    int i = blockIdx.x * 256 + threadIdx.x;
    if (i < N) {
        int r = rowstart[i] + bsums[blockIdx.x];
        rowstart[i] = r;
        cursor[i] = r;
    }
    if (i == 0 && blockIdx.x == 0) rowstart[N] = E;
}

// CSR fill: ed[pos] = {x[src], dinv[src] bits}; cols[pos] = src
__global__ __launch_bounds__(256) void k_fill(const int* __restrict__ src, const int* __restrict__ dst,
                                              const int* __restrict__ x, const float* __restrict__ dinv,
                                              int* __restrict__ cursor, int2* __restrict__ ed,
                                              int* __restrict__ cols, int E) {
    int e = blockIdx.x * 256 + threadIdx.x;
    if (e < E) {
        int d = dst[e];
        int s = src[e];
        int pos = atomicAdd(&cursor[d], 1);
        ed[pos] = make_int2(x[s], __float_as_int(dinv[s]));
        cols[pos] = s;
    }
}

// Fused node pipeline: 512 threads, block = 32 nodes, SINGLE phase-1 pass.
// Phase 1: 16 half-waves x 2 nodes. Quad-row gathers: lane=(p=lane>>3, f16=lane&7);
//   one 16B load covers 4 edge rows; f32 accum over 8 feats; shfl_xor(8,16) reduce.
// Phase 2: Hs = relu(Xs @ W1 + b1)   (8 waves: 2 row-tiles x 4 col-quarters, MFMA)
// Phase 3: P  = dinv * (Hs @ W2)     (same partition, MFMA)
__global__ __launch_bounds__(512) void k_mlp(const __half2* __restrict__ e16, const int* __restrict__ x,
                                             const float* __restrict__ dinv, const int* __restrict__ rs,
                                             const int2* __restrict__ ed, const _Float16* __restrict__ W1T,
                                             const float* __restrict__ b1, const _Float16* __restrict__ W2T,
                                             _Float16* __restrict__ P, int N) {
    __shared__ _Float16 Xs[32][72];    // 64-dim rows, stride 144B
    __shared__ _Float16 Hs[32][136];   // 128-dim rows, stride 272B
    int tid = threadIdx.x;
    int blk0 = blockIdx.x * 32;
    // ---- Phase 1 ----
    {
        int lane = tid & 31;
        int hw = tid >> 5;   // 0..15
        int p = lane >> 3;   // 0..3 quad
        int f16 = lane & 7;  // h8 slot (8 fp16 feats)
        const h8* e8 = (const h8*)e16;
        int nlA = hw * 2, nlB = nlA + 1;
        int gA = blk0 + nlA; if (gA >= N) gA = N - 1;
        int gB = blk0 + nlB; if (gB >= N) gB = N - 1;
        int cA0 = rs[gA], cA1 = rs[gA + 1];
        int cB0 = rs[gB], cB1 = rs[gB + 1];
        int baseA = (cA0 < cA1) ? cA1 - 1 : 0;
        int baseB = (cB0 < cB1) ? cB1 - 1 : 0;
        float dA = dinv[gA], dB = dinv[gB];
        h8 selfA = e8[(size_t)x[gA] * 8 + f16];
        h8 selfB = e8[(size_t)x[gB] * 8 + f16];
        float accA[8] = {}, accB[8] = {};
        // first batches of A and B issued together: 16 rows in flight
        {
            int eA0 = cA0 + p, eA1 = cA0 + 4 + p;
            int eB0 = cB0 + p, eB1 = cB0 + 4 + p;
            int2 rA0 = ed[(eA0 < cA1) ? eA0 : baseA];
            int2 rA1 = ed[(eA1 < cA1) ? eA1 : baseA];
            int2 rB0 = ed[(eB0 < cB1) ? eB0 : baseB];
            int2 rB1 = ed[(eB1 < cB1) ? eB1 : baseB];
            h8 tA0 = e8[(size_t)rA0.x * 8 + f16];
            h8 tA1 = e8[(size_t)rA1.x * 8 + f16];
            h8 tB0 = e8[(size_t)rB0.x * 8 + f16];
            h8 tB1 = e8[(size_t)rB1.x * 8 + f16];
            float wA0 = (eA0 < cA1) ? __int_as_float(rA0.y) : 0.f;
            float wA1 = (eA1 < cA1) ? __int_as_float(rA1.y) : 0.f;
            float wB0 = (eB0 < cB1) ? __int_as_float(rB0.y) : 0.f;
            float wB1 = (eB1 < cB1) ? __int_as_float(rB1.y) : 0.f;
#pragma unroll
            for (int f = 0; f < 8; ++f) {
                accA[f] = fmaf(wA1, (float)tA1[f], fmaf(wA0, (float)tA0[f], accA[f]));
                accB[f] = fmaf(wB1, (float)tB1[f], fmaf(wB0, (float)tB0[f], accB[f]));
            }
        }
        // tails (deg > 8)
        for (int eb = cA0 + 8; eb < cA1; eb += 8) {
            int e0 = eb + p, e1i = eb + 4 + p;
            int2 r0 = ed[(e0 < cA1) ? e0 : cA1 - 1];
            int2 r1 = ed[(e1i < cA1) ? e1i : cA1 - 1];
            h8 t0 = e8[(size_t)r0.x * 8 + f16];
            h8 t1 = e8[(size_t)r1.x * 8 + f16];
            float w0 = (e0 < cA1) ? __int_as_float(r0.y) : 0.f;
            float w1 = (e1i < cA1) ? __int_as_float(r1.y) : 0.f;
#pragma unroll
            for (int f = 0; f < 8; ++f)
                accA[f] = fmaf(w1, (float)t1[f], fmaf(w0, (float)t0[f], accA[f]));
        }
        for (int eb = cB0 + 8; eb < cB1; eb += 8) {
            int e0 = eb + p, e1i = eb + 4 + p;
            int2 r0 = ed[(e0 < cB1) ? e0 : cB1 - 1];
            int2 r1 = ed[(e1i < cB1) ? e1i : cB1 - 1];
            h8 t0 = e8[(size_t)r0.x * 8 + f16];
            h8 t1 = e8[(size_t)r1.x * 8 + f16];
            float w0 = (e0 < cB1) ? __int_as_float(r0.y) : 0.f;
            float w1 = (e1i < cB1) ? __int_as_float(r1.y) : 0.f;
#pragma unroll
            for (int f = 0; f < 8; ++f)
                accB[f] = fmaf(w1, (float)t1[f], fmaf(w0, (float)t0[f], accB[f]));
        }
        // cross-quad reduce + self + scale, p==0 writes
        h8 yA, yB;
#pragma unroll
        for (int f = 0; f < 8; ++f) {
            float a = accA[f];
            a += __shfl_xor(a, 8);
            a += __shfl_xor(a, 16);
            float b = accB[f];
            b += __shfl_xor(b, 8);
            b += __shfl_xor(b, 16);
            yA[f] = (_Float16)(dA * fmaf(dA, (float)selfA[f], a));
            yB[f] = (_Float16)(dB * fmaf(dB, (float)selfB[f], b));
        }
        if (p == 0) {
            *(h8*)&Xs[nlA][f16 * 8] = yA;
            *(h8*)&Xs[nlB][f16 * 8] = yB;
        }
    }
    __syncthreads();
    int l = tid & 63, wid = tid >> 6;    // 8 waves
    int r = l & 15, kg = l >> 4;
    int rb = wid & 1;                    // row tile: 16 rows
    int ch = wid >> 1;                   // col quarter: 32 cols
    // ---- Phase 2: Hs = relu(Xs @ W1 + b1), wave = 16 rows x 32 cols ----
    {
        f32x4 acc[2];
#pragma unroll
        for (int ct = 0; ct < 2; ++ct) acc[ct] = (f32x4){0.f, 0.f, 0.f, 0.f};
#pragma unroll
        for (int kc = 0; kc < 2; ++kc) {
            h8 a = *(const h8*)&Xs[rb * 16 + r][kc * 32 + kg * 8];
#pragma unroll
            for (int ct = 0; ct < 2; ++ct) {
                h8 b = *(const h8*)(W1T + (size_t)(ch * 32 + ct * 16 + r) * 64 + kc * 32 + kg * 8);
                acc[ct] = __builtin_amdgcn_mfma_f32_16x16x32_f16(a, b, acc[ct], 0, 0, 0);
            }
        }
#pragma unroll
        for (int ct = 0; ct < 2; ++ct) {
            float bias = b1[ch * 32 + ct * 16 + r];
#pragma unroll
            for (int i = 0; i < 4; ++i)
                Hs[rb * 16 + 4 * kg + i][ch * 32 + ct * 16 + r] =
                    (_Float16)fmaxf(acc[ct][i] + bias, 0.f);
        }
    }
    __syncthreads();
    // ---- Phase 3: P = dinv * (Hs @ W2), wave = 16 rows x 32 cols ----
    {
        f32x4 acc[2];
#pragma unroll
        for (int ct = 0; ct < 2; ++ct) acc[ct] = (f32x4){0.f, 0.f, 0.f, 0.f};
#pragma unroll
        for (int kc = 0; kc < 4; ++kc) {
            h8 a = *(const h8*)&Hs[rb * 16 + r][kc * 32 + kg * 8];
#pragma unroll
            for (int ct = 0; ct < 2; ++ct) {
                h8 b = *(const h8*)(W2T + (size_t)(ch * 32 + ct * 16 + r) * 128 + kc * 32 + kg * 8);
                acc[ct] = __builtin_amdgcn_mfma_f32_16x16x32_f16(a, b, acc[ct], 0, 0, 0);
            }
        }
        float dv[4];
#pragma unroll
        for (int i = 0; i < 4; ++i) {
            int gr = blk0 + rb * 16 + 4 * kg + i;
            dv[i] = (gr < N) ? dinv[gr] : 0.f;
        }
#pragma unroll
        for (int ct = 0; ct < 2; ++ct) {
#pragma unroll
            for (int i = 0; i < 4; ++i) {
                int gr = blk0 + rb * 16 + 4 * kg + i;
                if (gr < N)
                    P[(size_t)gr * 128 + ch * 32 + ct * 16 + r] = (_Float16)(acc[ct][i] * dv[i]);
            }
        }
    }
}

// Layer-2 + global_max_pool. 256-thr block = 8 half-waves x 2 nodes = 16 sorted nodes.
// 16B/lane parity gather: lane=(p=lane>>4, s=lane&15); one h8 load covers 2 edge rows;
// per-node 16-edge batch = 8 loads/lane; shfl_xor(16) cross-parity reduce; self added
// post-reduce. p==0 emits. LDS pool slots + one global emit per (block,graph,feature).
__global__ __launch_bounds__(256) void k_agg2pool(const h8* __restrict__ P8, const int* __restrict__ batch,
                                                  const float* __restrict__ dinv, const int* __restrict__ rs,
                                                  const int* __restrict__ cols, const float* __restrict__ b2,
                                                  float* __restrict__ pool, int N, int G) {
    __shared__ int lpool[4][128];
    int tid = threadIdx.x;
    lpool[tid >> 7][tid & 127] = 0;
    lpool[(tid >> 7) + 2][tid & 127] = 0;
    __syncthreads();
    int lane = tid & 31;
    int p = lane >> 4;   // parity (edge subset)
    int s = lane & 15;   // h8 slot: feats s*8..s*8+7
    int blk_n0 = blockIdx.x * 16;
    int gfirst = batch[(blk_n0 < N) ? blk_n0 : (N - 1)];
    int n0 = blk_n0 + (tid >> 5) * 2;
    if (n0 < N) {
        int nA = n0;
        int nB = (n0 + 1 < N) ? n0 + 1 : n0;
        int cA0 = rs[nA], cA1 = rs[nA + 1];
        int cB0 = rs[nB], cB1 = rs[nB + 1];
        bool hasA = cA0 < cA1, hasB = cB0 < cB1;
        h8 sA = P8[(size_t)nA * 16 + s];
        h8 sB = P8[(size_t)nB * 16 + s];
        float aA[8] = {}, aB[8] = {};
        // first 16-edge batches of A and B, dual-issued (8 loads/lane each)
        {
            h8 tA[8], tB[8];
            float wA[8], wB[8];
#pragma unroll
            for (int i = 0; i < 8; ++i) {
                int ei = cA0 + 2 * i + p;
                int ec = (ei < cA1) ? ei : (hasA ? cA1 - 1 : 0);
                tA[i] = P8[(size_t)cols[ec] * 16 + s];
                wA[i] = (ei < cA1) ? 1.f : 0.f;
            }
#pragma unroll
            for (int i = 0; i < 8; ++i) {
                int ei = cB0 + 2 * i + p;
                int ec = (ei < cB1) ? ei : (hasB ? cB1 - 1 : 0);
                tB[i] = P8[(size_t)cols[ec] * 16 + s];
                wB[i] = (ei < cB1) ? 1.f : 0.f;
            }
#pragma unroll
            for (int i = 0; i < 8; ++i)
#pragma unroll
                for (int f = 0; f < 8; ++f) aA[f] = fmaf(wA[i], (float)tA[i][f], aA[f]);
#pragma unroll
            for (int i = 0; i < 8; ++i)
#pragma unroll
                for (int f = 0; f < 8; ++f) aB[f] = fmaf(wB[i], (float)tB[i][f], aB[f]);
        }
        // tails (deg > 16)
        for (int eb = cA0 + 16; eb < cA1; eb += 16) {
            h8 t[8];
            float w[8];
#pragma unroll
            for (int i = 0; i < 8; ++i) {
                int ei = eb + 2 * i + p;
                int ec = (ei < cA1) ? ei : cA1 - 1;
                t[i] = P8[(size_t)cols[ec] * 16 + s];
                w[i] = (ei < cA1) ? 1.f : 0.f;
            }
#pragma unroll
            for (int i = 0; i < 8; ++i)
#pragma unroll
                for (int f = 0; f < 8; ++f) aA[f] = fmaf(w[i], (float)t[i][f], aA[f]);
        }
        for (int eb = cB0 + 16; eb < cB1; eb += 16) {
            h8 t[8];
            float w[8];
#pragma unroll
            for (int i = 0; i < 8; ++i) {
                int ei = eb + 2 * i + p;
                int ec = (ei < cB1) ? ei : cB1 - 1;
                t[i] = P8[(size_t)cols[ec] * 16 + s];
                w[i] = (ei < cB1) ? 1.f : 0.f;
            }
#pragma unroll
            for (int i = 0; i < 8; ++i)
#pragma unroll
                for (int f = 0; f < 8; ++f) aB[f] = fmaf(w[i], (float)t[i][f], aB[f]);
        }
        // cross-parity reduce, then self + bias + relu
        float dA = dinv[nA], dB = dinv[nB];
        int gA = batch[nA], gB = batch[nB];
        float4 bb0 = *(const float4*)&b2[s * 8];
        float4 bb1 = *(const float4*)&b2[s * 8 + 4];
        float bv[8] = {bb0.x, bb0.y, bb0.z, bb0.w, bb1.x, bb1.y, bb1.z, bb1.w};
        float zA[8], zB[8];
#pragma unroll
        for (int f = 0; f < 8; ++f) {
            float a = aA[f] + __shfl_xor(aA[f], 16);
            float b = aB[f] + __shfl_xor(aB[f], 16);
            zA[f] = fmaxf(fmaf(dA, (float)sA[f] + a, bv[f]), 0.f);
            zB[f] = fmaxf(fmaf(dB, (float)sB[f] + b, bv[f]), 0.f);
        }
        auto emit = [&](int g, const float* m) {
            if (p != 0) return;  // parities hold identical values post-reduce
            int slot = g - gfirst;
            if (slot < 4) {
#pragma unroll
                for (int f = 0; f < 8; ++f) {
                    int ff = (f + s) & 7;  // bank rotation
                    if (m[ff] > 0.f) atomicMax(&lpool[slot][s * 8 + ff], __float_as_int(m[ff]));
                }
            } else {
                float* pg = pool + (size_t)g * 128 + s * 8;
#pragma unroll
                for (int f = 0; f < 8; ++f)
                    if (m[f] > 0.f) atomicMax((int*)(pg + f), __float_as_int(m[f]));
            }
        };
        if (gA == gB) {
            float m[8];
#pragma unroll
            for (int f = 0; f < 8; ++f) m[f] = fmaxf(zA[f], zB[f]);
            emit(gA, m);
        } else {
            emit(gA, zA);
            emit(gB, zB);
        }
    }
    __syncthreads();
    {
        int f = tid & 127;
        for (int sl = tid >> 7; sl < 4; sl += 2) {
            int v = lpool[sl][f];
            if (v > 0) atomicMax((int*)&pool[(size_t)(gfirst + sl) * 128 + f], v);
        }
    }
}

// out[g][c] = blin[c] + sum_f pool[g][f] * Wlin[f][c]
__global__ __launch_bounds__(256) void k_final(const float* __restrict__ pool, const float* __restrict__ Wlin,
                                               const float* __restrict__ blin, float* __restrict__ out, int G) {
    int t = blockIdx.x * 256 + threadIdx.x;
    if (t >= G * 10) return;
    int g = t / 10, c = t % 10;
    float acc = blin[c];
    const float* pr = pool + (size_t)g * 128;
#pragma unroll 8
    for (int f = 0; f < 128; ++f) acc = fmaf(pr[f], Wlin[f * 10 + c], acc);
    out[t] = acc;
}

extern "C" void kernel_launch(void* const* d_in, const int* in_sizes, int n_in,
                              void* d_out, int out_size, void* d_ws, size_t ws_size,
                              hipStream_t stream) {
    const int* x = (const int*)d_in[0];
    const int* ei = (const int*)d_in[1];
    const int* batch = (const int*)d_in[2];
    const float* emb = (const float*)d_in[4];
    const float* W1 = (const float*)d_in[5];
    const float* b1 = (const float*)d_in[6];
    const float* W2 = (const float*)d_in[7];
    const float* b2 = (const float*)d_in[8];
    const float* Wlin = (const float*)d_in[9];
    const float* blin = (const float*)d_in[10];
    float* out = (float*)d_out;

    int N = in_sizes[0];
    int E = in_sizes[1] / 2;
    int VOCAB = in_sizes[4] / 64;
    int G = out_size / 10;
    const int* srcp = ei;
    const int* dstp = ei + E;

    char* p = (char*)d_ws;
    auto alloc = [&](size_t bytes) -> char* {
        char* r = p;
        p += (bytes + 255) & ~(size_t)255;
        return r;
    };
    int* deg = (int*)alloc((size_t)N * 4);
    int* cursor = (int*)alloc((size_t)N * 4);
    int* rowstart = (int*)alloc((size_t)(N + 1) * 4);
    int* bsums = (int*)alloc(512 * 4);
    float* dinv = (float*)alloc((size_t)N * 4);
    int2* ed = (int2*)alloc((size_t)E * 8);
    int* cols = (int*)alloc((size_t)E * 4);
    _Float16* e16 = (_Float16*)alloc((size_t)VOCAB * 64 * 2);
    _Float16* W1T = (_Float16*)alloc(128 * 64 * 2);
    _Float16* W2T = (_Float16*)alloc(128 * 128 * 2);
    _Float16* P = (_Float16*)alloc((size_t)N * 128 * 2);
    float* pool = (float*)alloc((size_t)G * 128 * 4);

    int gE = (E + 255) / 256;
    int gN = (N + 255) / 256;  // 391 <= 512 (scan2 capacity)
    int nEmbF = VOCAB * 64;
    int nCast = (nEmbF / 4 + 255) / 256;

    int n4i = N / 4, p4i = G * 128 / 4;
    int zg = ((n4i > p4i ? n4i : p4i) + 255) / 256;
    k_zero<<<zg, 256, 0, stream>>>((int4*)deg, n4i, (int4*)pool, p4i);
    k_degprep<<<gE + nCast + 32 + 64, 256, 0, stream>>>(dstp, deg, E, emb, (__half2*)e16, W1, W1T,
                                                        W2, W2T, nEmbF, gE, nCast);
    k_scan1<<<gN, 256, 0, stream>>>(deg, rowstart, bsums, dinv, N);
    k_scan2<<<1, 512, 0, stream>>>(bsums, gN);
    k_scan3<<<gN, 256, 0, stream>>>(rowstart, cursor, bsums, N, E);
    k_fill<<<gE, 256, 0, stream>>>(srcp, dstp, x, dinv, cursor, ed, cols, E);
    k_mlp<<<(N + 31) / 32, 512, 0, stream>>>((const __half2*)e16, x, dinv, rowstart, ed, W1T, b1,
                                             W2T, P, N);
    k_agg2pool<<<(N + 15) / 16, 256, 0, stream>>>((const h8*)P, batch, dinv, rowstart, cols,
                                                  b2, pool, N, G);
    k_final<<<(G * 10 + 255) / 256, 256, 0, stream>>>(pool, Wlin, blin, out, G);
}